// Round 1
// baseline (2646.001 us; speedup 1.0000x reference)
//
#include <hip/hip_runtime.h>

#define T_STEPS 100
#define BATCH   1024
#define NIN     784
#define NHID    1000
#define NOUT    10

// ---------------------------------------------------------------------------
// GEMM1: C[M x NHID] = A[M x NIN] @ W1^T + b1   (A = x chunk, row-major, K=784)
// 128x128 block tile, BK=8, 8x8 microtile per thread, 256 threads.
// ---------------------------------------------------------------------------
__global__ __launch_bounds__(256) void gemm1_kernel(
    const float* __restrict__ A, const float* __restrict__ W1,
    const float* __restrict__ b1, float* __restrict__ C) {
  __shared__ float As[8][128];
  __shared__ float Bs[8][128];

  const int tid = threadIdx.x;
  const int m0 = blockIdx.x * 128;
  const int n0 = blockIdx.y * 128;
  const int tx = tid & 15;        // 0..15 -> n microtile
  const int ty = tid >> 4;        // 0..15 -> m microtile

  // staging assignment: each thread loads one float4 of A and one of B per K-tile
  const int r  = tid >> 1;        // 0..127 row within tile
  const int kc = (tid & 1) * 4;   // 0 or 4

  const float* arow = A + (size_t)(m0 + r) * NIN + kc;
  const int nrow = n0 + r;
  const bool bok = (nrow < NHID);
  const float* brow = bok ? (W1 + (size_t)nrow * NIN + kc) : W1;

  float acc[8][8];
#pragma unroll
  for (int i = 0; i < 8; i++)
#pragma unroll
    for (int j = 0; j < 8; j++) acc[i][j] = 0.0f;

  for (int kt = 0; kt < NIN; kt += 8) {
    float4 av = *(const float4*)(arow + kt);
    float4 bv = make_float4(0.f, 0.f, 0.f, 0.f);
    if (bok) bv = *(const float4*)(brow + kt);

    As[kc + 0][r] = av.x; As[kc + 1][r] = av.y;
    As[kc + 2][r] = av.z; As[kc + 3][r] = av.w;
    Bs[kc + 0][r] = bv.x; Bs[kc + 1][r] = bv.y;
    Bs[kc + 2][r] = bv.z; Bs[kc + 3][r] = bv.w;
    __syncthreads();

#pragma unroll
    for (int kk = 0; kk < 8; kk++) {
      float a[8], b[8];
      *(float4*)&a[0] = *(const float4*)&As[kk][ty * 8];
      *(float4*)&a[4] = *(const float4*)&As[kk][ty * 8 + 4];
      *(float4*)&b[0] = *(const float4*)&Bs[kk][tx * 8];
      *(float4*)&b[4] = *(const float4*)&Bs[kk][tx * 8 + 4];
#pragma unroll
      for (int i = 0; i < 8; i++)
#pragma unroll
        for (int j = 0; j < 8; j++) acc[i][j] = fmaf(a[i], b[j], acc[i][j]);
    }
    __syncthreads();
  }

  const int nc = n0 + tx * 8;
  if (nc < NHID) {  // NHID % 8 == 0 so whole 8-wide chunk is in or out
    float4 bb0 = *(const float4*)(b1 + nc);
    float4 bb1 = *(const float4*)(b1 + nc + 4);
#pragma unroll
    for (int i = 0; i < 8; i++) {
      float* crow = C + (size_t)(m0 + ty * 8 + i) * NHID + nc;
      float4 v0 = make_float4(acc[i][0] + bb0.x, acc[i][1] + bb0.y,
                              acc[i][2] + bb0.z, acc[i][3] + bb0.w);
      float4 v1 = make_float4(acc[i][4] + bb1.x, acc[i][5] + bb1.y,
                              acc[i][6] + bb1.z, acc[i][7] + bb1.w);
      *(float4*)crow = v0;
      *(float4*)(crow + 4) = v1;
    }
  }
}

// ---------------------------------------------------------------------------
// scan1: per-(b,h) LIF update over ct timesteps. Overwrites cur1 with spk1.
// buf layout: [ct][BATCH*NHID]
// ---------------------------------------------------------------------------
__global__ __launch_bounds__(256) void scan1_kernel(
    float* __restrict__ buf, float* __restrict__ mem1, int ct) {
  const int j = blockIdx.x * 256 + threadIdx.x;  // 0 .. BATCH*NHID-1
  float m = mem1[j];
  for (int t = 0; t < ct; t++) {
    size_t idx = (size_t)t * (BATCH * NHID) + j;
    float c = buf[idx];
    float rst = (m > 1.0f) ? 1.0f : 0.0f;
    m = 0.9f * m + c - rst;
    buf[idx] = (m > 1.0f) ? 1.0f : 0.0f;
  }
  mem1[j] = m;
}

// ---------------------------------------------------------------------------
// GEMM2: cur2[row][o] = sum_h spk1[row][h] * W2[o][h] + b2[o]
// one wave per row; 10 accumulators; butterfly reduce.
// ---------------------------------------------------------------------------
__global__ __launch_bounds__(256) void gemm2_kernel(
    const float* __restrict__ spk1, const float* __restrict__ W2,
    const float* __restrict__ b2, float* __restrict__ cur2, int rows) {
  const int lane = threadIdx.x & 63;
  const int row = blockIdx.x * 4 + (threadIdx.x >> 6);
  if (row >= rows) return;

  const float* srow = spk1 + (size_t)row * NHID;
  float acc[NOUT];
#pragma unroll
  for (int o = 0; o < NOUT; o++) acc[o] = 0.0f;

  for (int h = lane; h < NHID; h += 64) {
    float s = srow[h];
#pragma unroll
    for (int o = 0; o < NOUT; o++) acc[o] = fmaf(s, W2[o * NHID + h], acc[o]);
  }
#pragma unroll
  for (int off = 32; off > 0; off >>= 1) {
#pragma unroll
    for (int o = 0; o < NOUT; o++) acc[o] += __shfl_xor(acc[o], off, 64);
  }
  if (lane == 0) {
#pragma unroll
    for (int o = 0; o < NOUT; o++) cur2[(size_t)row * NOUT + o] = acc[o] + b2[o];
  }
}

// ---------------------------------------------------------------------------
// scan2: per-(b,o) LIF update; writes spk2 and mem2 into d_out.
// out layout: spk_rec [T][B][NOUT] then mem_rec [T][B][NOUT]
// ---------------------------------------------------------------------------
__global__ __launch_bounds__(256) void scan2_kernel(
    const float* __restrict__ cur2, float* __restrict__ mem2,
    float* __restrict__ out, int t0, int ct) {
  const int j = blockIdx.x * 256 + threadIdx.x;  // 0 .. BATCH*NOUT-1
  float m = mem2[j];
  const size_t memofs = (size_t)T_STEPS * BATCH * NOUT;
  for (int t = 0; t < ct; t++) {
    float c = cur2[(size_t)t * (BATCH * NOUT) + j];
    float rst = (m > 1.0f) ? 1.0f : 0.0f;
    m = 0.9f * m + c - rst;
    float s = (m > 1.0f) ? 1.0f : 0.0f;
    size_t o = (size_t)(t0 + t) * (BATCH * NOUT) + j;
    out[o] = s;
    out[memofs + o] = m;
  }
  mem2[j] = m;
}

// ---------------------------------------------------------------------------
extern "C" void kernel_launch(void* const* d_in, const int* in_sizes, int n_in,
                              void* d_out, int out_size, void* d_ws, size_t ws_size,
                              hipStream_t stream) {
  const float* x  = (const float*)d_in[0];
  const float* W1 = (const float*)d_in[1];
  const float* b1 = (const float*)d_in[2];
  const float* W2 = (const float*)d_in[3];
  const float* b2 = (const float*)d_in[4];
  float* out = (float*)d_out;

  float* mem1 = (float*)d_ws;                              // B*NHID
  float* mem2 = mem1 + (size_t)BATCH * NHID;               // B*NOUT
  float* buf  = mem2 + (size_t)BATCH * NOUT;               // chunk buffers

  const size_t fixedB = ((size_t)BATCH * NHID + (size_t)BATCH * NOUT) * sizeof(float);
  const size_t perTB  = ((size_t)BATCH * (NHID + NOUT)) * sizeof(float);

  long long avail = (long long)ws_size - (long long)fixedB;
  int chunkT = (avail > 0) ? (int)(avail / (long long)perTB) : 1;
  if (chunkT < 1) chunkT = 1;
  if (chunkT > T_STEPS) chunkT = T_STEPS;

  hipMemsetAsync(d_ws, 0, fixedB, stream);

  float* cur2buf = buf + (size_t)chunkT * BATCH * NHID;

  for (int t0 = 0; t0 < T_STEPS; t0 += chunkT) {
    int ct = (T_STEPS - t0 < chunkT) ? (T_STEPS - t0) : chunkT;
    int M = ct * BATCH;

    dim3 g1(M / 128, (NHID + 127) / 128);
    gemm1_kernel<<<g1, 256, 0, stream>>>(x + (size_t)t0 * BATCH * NIN, W1, b1, buf);

    scan1_kernel<<<(BATCH * NHID) / 256, 256, 0, stream>>>(buf, mem1, ct);

    gemm2_kernel<<<(M + 3) / 4, 256, 0, stream>>>(buf, W2, b2, cur2buf, M);

    scan2_kernel<<<(BATCH * NOUT) / 256, 256, 0, stream>>>(cur2buf, mem2, out, t0, ct);
  }
}